// Round 19
// baseline (32.945 us; speedup 1.0000x reference)
//
#include <hip/hip_runtime.h>

#define TAPS 5
#define BLK 512

// antireflect fetch from a global plane
__device__ __forceinline__ float ldcg(const float* __restrict__ row, int j, int N) {
    if ((unsigned)j < (unsigned)N) return row[j];
    const int e = (j < 0) ? 0 : N - 1;
    const int r = (j < 0) ? -j : 2 * (N - 1) - j;
    return 2.f * row[e] - row[r];
}
__device__ __forceinline__ float ldrc(const float* __restrict__ p, int m, int j, int N) {
    if ((unsigned)m < (unsigned)N) return ldcg(p + (size_t)m * N, j, N);
    const int e = (m < 0) ? 0 : N - 1;
    const int r = (m < 0) ? -m : 2 * (N - 1) - m;
    return 2.f * ldcg(p + (size_t)e * N, j, N) - ldcg(p + (size_t)r * N, j, N);
}
__device__ __forceinline__ void fma4(float4& a, float c, const float4& v) {
    a.x += c * v.x; a.y += c * v.y; a.z += c * v.z; a.w += c * v.w;
}
__device__ __forceinline__ float4 ldsf4(const float* p) { return *reinterpret_cast<const float4*>(p); }
__device__ __forceinline__ void stsf4(float* p, const float4& v) { *reinterpret_cast<float4*>(p) = v; }
__device__ __forceinline__ void stsf2(float* p, float a, float b) {
    *reinterpret_cast<float2*>(p) = make_float2(a, b);
}
__device__ __forceinline__ void gl_lds16(const float* g, float* l) {
    __builtin_amdgcn_global_load_lds(
        (const __attribute__((address_space(1))) void*)g,
        (__attribute__((address_space(3))) void*)l, 16, 0, 0);
}

// LDS floats: ST 0..4320 | SD 4320..9440 | I0 9440..10016 | I1 10016..11456
#define OFF_SD 4320
#define OFF_I0 9440
#define OFF_I1 10016
#define SM_FLOATS 11456

__global__ __launch_bounds__(BLK)
void idwt3(const float* __restrict__ ss,
           const float* __restrict__ sd0, const float* __restrict__ sd1, const float* __restrict__ sd2,
           const float* __restrict__ ds0, const float* __restrict__ ds1, const float* __restrict__ ds2,
           const float* __restrict__ dd0, const float* __restrict__ dd1, const float* __restrict__ dd2,
           const float* __restrict__ h, const float* __restrict__ g_,
           float* __restrict__ out) {
    extern __shared__ float sm[];
    float* ST = sm;
    float* SD = sm + OFF_SD;
    float* I0 = sm + OFF_I0;   // [24][24], row0 = R0/4-4, col0 = W0/4-4
    float* I1 = sm + OFF_I1;   // [36][40], row0 = R0/2-2, x-grid col0 = W0/2-4

    const int hw = blockIdx.x;
    const int lb = (hw & 7) * 256 + (hw >> 3);   // XCD swizzle
    const int b  = lb >> 8;
    const int tile = lb & 255;
    const int tr = tile >> 4, tc = tile & 15;
    const int R0 = tr * 64, W0 = tc * 64;
    const int tid = threadIdx.x;

    float hk0[TAPS], hk1[TAPS], gk0[TAPS], gk1[TAPS];
#pragma unroll
    for (int t = 0; t < TAPS; ++t) {
        hk0[t] = h[8 - 2 * t];  hk1[t] = h[9 - 2 * t];
        gk0[t] = g_[8 - 2 * t]; gk1[t] = g_[9 - 2 * t];
    }

    const float* pss  = ss  + (size_t)b * 16384;
    const float* psd2 = sd2 + (size_t)b * 16384;
    const float* pds2 = ds2 + (size_t)b * 16384;
    const float* pdd2 = dd2 + (size_t)b * 16384;
    const float* psd1 = sd1 + (size_t)b * 65536;
    const float* pds1 = ds1 + (size_t)b * 65536;
    const float* pdd1 = dd1 + (size_t)b * 65536;
    const float* psd0 = sd0 + (size_t)b * 262144;
    const float* pds0 = ds0 + (size_t)b * 262144;
    const float* pdd0 = dd0 + (size_t)b * 262144;

    const bool inner = (tr >= 1) && (tr <= 14) && (tc >= 1) && (tc <= 14);

    if (inner) {
        // ======== FAST PATH ========
        if (tid < 256) {   // A2: 4 planes [16][16]
            const int r0g = 8 * tr - 4, c0g = 8 * tc - 4;
            const int q = tid >> 6, rm = tid & 63, r = rm >> 2, c4 = rm & 3;
            const float* p = (q == 0) ? pss : (q == 1) ? psd2 : (q == 2) ? pds2 : pdd2;
            gl_lds16(p + (r0g + r) * 128 + c0g + 4 * c4, ST + 4 * tid);
        }
        __syncthreads();
        // vert2 -> S2 [24][16] @SD, D2 @SD+384
        if (tid < 48) {
            const int i = tid >> 2, fc = (tid & 3) * 4;
            float4 s0{0,0,0,0}, s1{0,0,0,0}, d0{0,0,0,0}, d1{0,0,0,0};
#pragma unroll
            for (int t = 0; t < TAPS; ++t) {
                const int rr = (i + t) * 16 + fc;
                const float4 va = ldsf4(ST + rr);
                const float4 vb = ldsf4(ST + 256 + rr);
                const float4 vc = ldsf4(ST + 512 + rr);
                const float4 vd = ldsf4(ST + 768 + rr);
                fma4(s0, hk0[t], va); fma4(s0, gk0[t], vb);
                fma4(s1, hk1[t], va); fma4(s1, gk1[t], vb);
                fma4(d0, hk0[t], vc); fma4(d0, gk0[t], vd);
                fma4(d1, hk1[t], vc); fma4(d1, gk1[t], vd);
            }
            const int ri = 2 * i;
            stsf4(SD + ri * 16 + fc, s0); stsf4(SD + (ri + 1) * 16 + fc, s1);
            stsf4(SD + 384 + ri * 16 + fc, d0); stsf4(SD + 384 + (ri + 1) * 16 + fc, d1);
        }
        __syncthreads();
        if (tid < 396) {   // issue A1: 3 planes [22][24] (overlaps horiz2)
            const int a1r0 = 16 * tr - 3, a1c0 = 16 * tc - 4;
            const int q = tid / 132, rm = tid - q * 132, r = rm / 6, c4 = rm - r * 6;
            const float* p = (q == 0) ? psd1 : (q == 1) ? pds1 : pdd1;
            gl_lds16(p + (a1r0 + r) * 256 + a1c0 + 4 * c4, ST + 4 * tid);
        }
        // horiz2 -> I0 [24][24]: 72 chunk items (4 pc each), all b128
        if (tid < 72) {
            const int ri = tid / 3, pc0 = (tid - ri * 3) * 4;
            float sv[8], dv[8];
            *reinterpret_cast<float4*>(&sv[0]) = ldsf4(SD + ri * 16 + pc0);
            *reinterpret_cast<float4*>(&sv[4]) = ldsf4(SD + ri * 16 + pc0 + 4);
            *reinterpret_cast<float4*>(&dv[0]) = ldsf4(SD + 384 + ri * 16 + pc0);
            *reinterpret_cast<float4*>(&dv[4]) = ldsf4(SD + 384 + ri * 16 + pc0 + 4);
            float o[8];
#pragma unroll
            for (int j = 0; j < 4; ++j) {
                float o0 = 0.f, o1 = 0.f;
#pragma unroll
                for (int t = 0; t < TAPS; ++t) {
                    o0 += hk0[t] * sv[j + t] + gk0[t] * dv[j + t];
                    o1 += hk1[t] * sv[j + t] + gk1[t] * dv[j + t];
                }
                o[2 * j] = o0; o[2 * j + 1] = o1;
            }
            stsf4(I0 + ri * 24 + 2 * pc0,     make_float4(o[0], o[1], o[2], o[3]));
            stsf4(I0 + ri * 24 + 2 * pc0 + 4, make_float4(o[4], o[5], o[6], o[7]));
        }
        __syncthreads();   // drains A1 loads
        // vert1: row-pair items -> S1 [36][28] @SD, D1 @SD+1008 (54 items)
        if (tid < 54) {
            const int ip = tid / 6, fc = (tid - ip * 6) * 4;
            float4 sA0{0,0,0,0}, sA1{0,0,0,0}, dA0{0,0,0,0}, dA1{0,0,0,0};
            float4 sB0{0,0,0,0}, sB1{0,0,0,0}, dB0{0,0,0,0}, dB1{0,0,0,0};
#pragma unroll
            for (int r = 0; r < 6; ++r) {
                const float4 va = ldsf4(I0 + (2 * ip + r + 1) * 24 + fc);
                const int ar = (2 * ip + r) * 24 + fc;
                const float4 vb = ldsf4(ST + ar);
                const float4 vc = ldsf4(ST + 528 + ar);
                const float4 vd = ldsf4(ST + 1056 + ar);
                if (r < 5) {
                    fma4(sA0, hk0[r], va); fma4(sA0, gk0[r], vb);
                    fma4(sA1, hk1[r], va); fma4(sA1, gk1[r], vb);
                    fma4(dA0, hk0[r], vc); fma4(dA0, gk0[r], vd);
                    fma4(dA1, hk1[r], vc); fma4(dA1, gk1[r], vd);
                }
                if (r >= 1) {
                    const int t = r - 1;
                    fma4(sB0, hk0[t], va); fma4(sB0, gk0[t], vb);
                    fma4(sB1, hk1[t], va); fma4(sB1, gk1[t], vb);
                    fma4(dB0, hk0[t], vc); fma4(dB0, gk0[t], vd);
                    fma4(dB1, hk1[t], vc); fma4(dB1, gk1[t], vd);
                }
            }
            const int r4 = 4 * ip;
            stsf4(SD + (r4    ) * 28 + fc, sA0); stsf4(SD + (r4 + 1) * 28 + fc, sA1);
            stsf4(SD + (r4 + 2) * 28 + fc, sB0); stsf4(SD + (r4 + 3) * 28 + fc, sB1);
            stsf4(SD + 1008 + (r4    ) * 28 + fc, dA0); stsf4(SD + 1008 + (r4 + 1) * 28 + fc, dA1);
            stsf4(SD + 1008 + (r4 + 2) * 28 + fc, dB0); stsf4(SD + 1008 + (r4 + 3) * 28 + fc, dB1);
        }
        __syncthreads();
        {   // issue A0: 3 planes [36][40] (overlaps horiz1)
            const int a0r0 = 32 * tr - 2, a0c0 = 32 * tc - 4;
#pragma unroll
            for (int k = 0; k < 3; ++k) {
                const int e = tid + BLK * k;
                if (e < 1080) {
                    const int q = e / 360, rm = e - q * 360, r = rm / 10, c4 = rm - r * 10;
                    const float* p = (q == 0) ? psd0 : (q == 1) ? pds0 : pdd0;
                    gl_lds16(p + (a0r0 + r) * 512 + a0c0 + 4 * c4, ST + 4 * e);
                }
            }
        }
        // horiz1 -> I1 x-grid: 180 chunk items (36 rows x 5 chunks), b128 reads
        if (tid < 180) {
            const int ri = tid / 5, cu = tid - ri * 5;
            const int pc0 = 4 * cu;
            const int npc = (cu < 4) ? 4 : 2;
            float sv[12], dv[12];
            *reinterpret_cast<float4*>(&sv[0]) = ldsf4(SD + ri * 28 + pc0);
            *reinterpret_cast<float4*>(&sv[4]) = ldsf4(SD + ri * 28 + pc0 + 4);
            *reinterpret_cast<float4*>(&sv[8]) = ldsf4(SD + ri * 28 + pc0 + 8);
            *reinterpret_cast<float4*>(&dv[0]) = ldsf4(SD + 1008 + ri * 28 + pc0);
            *reinterpret_cast<float4*>(&dv[4]) = ldsf4(SD + 1008 + ri * 28 + pc0 + 4);
            *reinterpret_cast<float4*>(&dv[8]) = ldsf4(SD + 1008 + ri * 28 + pc0 + 8);
#pragma unroll
            for (int j = 0; j < 4; ++j) {
                if (j < npc) {
                    float o0 = 0.f, o1 = 0.f;
#pragma unroll
                    for (int t = 0; t < TAPS; ++t) {
                        o0 += hk0[t] * sv[j + 1 + t] + gk0[t] * dv[j + 1 + t];
                        o1 += hk1[t] * sv[j + 1 + t] + gk1[t] * dv[j + 1 + t];
                    }
                    stsf2(I1 + ri * 40 + 2 * (pc0 + j) + 2, o0, o1);
                }
            }
        }
        __syncthreads();   // drains A0 loads
    } else {
        // ======== EDGE PATH (unchanged from R18; S1/D1 stride 24) ========
        {
            const int r0g = (R0 >> 3) - 4, c0g = (W0 >> 3) - 4;
            for (int e = tid; e < 1024; e += BLK) {
                const int q = e >> 8, rm = e & 255;
                const float* p = (q == 0) ? pss : (q == 1) ? psd2 : (q == 2) ? pds2 : pdd2;
                ST[e] = ldrc(p, r0g + (rm >> 4), c0g + (rm & 15), 128);
            }
        }
        __syncthreads();
        {
            const int lo = max((R0 >> 3) - 2, 0), hi = min((R0 >> 3) + 10, 128);
            const int a2r0 = (R0 >> 3) - 4;
            const int cnt = (hi - lo) * 4;
            for (int e = tid; e < cnt; e += BLK) {
                const int i = e >> 2, fc = (e & 3) * 4;
                const int n = lo + i;
                float4 s0{0,0,0,0}, s1{0,0,0,0}, d0{0,0,0,0}, d1{0,0,0,0};
#pragma unroll
                for (int t = 0; t < TAPS; ++t) {
                    const int rr = (n - 2 + t - a2r0) * 16 + fc;
                    const float4 va = ldsf4(ST + rr);
                    const float4 vb = ldsf4(ST + 256 + rr);
                    const float4 vc = ldsf4(ST + 512 + rr);
                    const float4 vd = ldsf4(ST + 768 + rr);
                    fma4(s0, hk0[t], va); fma4(s0, gk0[t], vb);
                    fma4(s1, hk1[t], va); fma4(s1, gk1[t], vb);
                    fma4(d0, hk0[t], vc); fma4(d0, gk0[t], vd);
                    fma4(d1, hk1[t], vc); fma4(d1, gk1[t], vd);
                }
                const int ri = 2 * (n - ((R0 >> 3) - 2));
                stsf4(SD + ri * 16 + fc, s0); stsf4(SD + (ri + 1) * 16 + fc, s1);
                stsf4(SD + 384 + ri * 16 + fc, d0); stsf4(SD + 384 + (ri + 1) * 16 + fc, d1);
            }
        }
        __syncthreads();
        float rA1[4];
        {
            const int a1r0 = (R0 >> 2) - 3, a1c0 = (W0 >> 2) - 4;
#pragma unroll
            for (int k = 0; k < 4; ++k) {
                const int e = tid + BLK * k;
                if (e < 1584) {
                    const int q = e / 528, rm = e - q * 528;
                    const float* p = (q == 0) ? psd1 : (q == 1) ? pds1 : pdd1;
                    rA1[k] = ldrc(p, a1r0 + rm / 24, a1c0 + rm % 24, 256);
                }
            }
        }
        {
            const int i0r0 = (R0 >> 2) - 4;
            const int riLo = max(0, -i0r0), riHi = min(24, 256 - i0r0);
            const int pcLo = max(0, -((W0 >> 3) - 2)), pcHi = min(12, 128 - ((W0 >> 3) - 2));
            const int np = pcHi - pcLo, cnt = (riHi - riLo) * np;
            for (int e = tid; e < cnt; e += BLK) {
                const int ri = riLo + e / np, pc = pcLo + e % np;
                float o0 = 0.f, o1 = 0.f;
#pragma unroll
                for (int t = 0; t < TAPS; ++t) {
                    const float sv = SD[ri * 16 + pc + t];
                    const float dv = SD[384 + ri * 16 + pc + t];
                    o0 += hk0[t] * sv + gk0[t] * dv;
                    o1 += hk1[t] * sv + gk1[t] * dv;
                }
                I0[ri * 24 + 2 * pc] = o0; I0[ri * 24 + 2 * pc + 1] = o1;
            }
        }
#pragma unroll
        for (int k = 0; k < 4; ++k) { const int e = tid + BLK * k; if (e < 1584) ST[e] = rA1[k]; }
        __syncthreads();
        {
            const int i0r0 = (R0 >> 2) - 4, i0c0 = (W0 >> 2) - 4;
            const int riLo = max(0, -i0r0), riHi = min(24, 256 - i0r0), nr = riHi - riLo;
            const int zL = max(0, -i0c0), eR = min(24, 256 - i0c0);
            if (zL > 0) for (int e = tid; e < nr * zL; e += BLK) {
                const int ri = riLo + e / zL, vc = e % zL;
                I0[ri * 24 + vc] = 2.f * I0[ri * 24 + zL] - I0[ri * 24 + 2 * zL - vc];
            }
            if (eR < 24) { const int nv = 24 - eR;
                for (int e = tid; e < nr * nv; e += BLK) {
                    const int ri = riLo + e / nv, vc = eR + e % nv;
                    I0[ri * 24 + vc] = 2.f * I0[ri * 24 + eR - 1] - I0[ri * 24 + 2 * (eR - 1) - vc];
                } }
        }
        __syncthreads();
        {
            const int i0r0 = (R0 >> 2) - 4;
            const int zT = max(0, -i0r0), eB = min(24, 256 - i0r0);
            if (zT > 0) for (int e = tid; e < zT * 24; e += BLK) {
                const int vr = e / 24, c = e % 24;
                I0[vr * 24 + c] = 2.f * I0[zT * 24 + c] - I0[(2 * zT - vr) * 24 + c];
            }
            if (eB < 24) { const int nv = 24 - eB;
                for (int e = tid; e < nv * 24; e += BLK) {
                    const int vr = eB + e / 24, c = e % 24;
                    I0[vr * 24 + c] = 2.f * I0[(eB - 1) * 24 + c] - I0[(2 * (eB - 1) - vr) * 24 + c];
                } }
        }
        __syncthreads();
        {
            const int lo = max((R0 >> 2) - 1, 0), hi = min((R0 >> 2) + 17, 256);
            const int i0r0 = (R0 >> 2) - 4, a1r0 = (R0 >> 2) - 3;
            const int cnt = (hi - lo) * 6;
            for (int e = tid; e < cnt; e += BLK) {
                const int i = e / 6, fc = (e % 6) * 4;
                const int n = lo + i;
                float4 s0{0,0,0,0}, s1{0,0,0,0}, d0{0,0,0,0}, d1{0,0,0,0};
#pragma unroll
                for (int t = 0; t < TAPS; ++t) {
                    const int m = n - 2 + t;
                    const float4 va = ldsf4(I0 + (m - i0r0) * 24 + fc);
                    const int ar = (m - a1r0) * 24 + fc;
                    const float4 vb = ldsf4(ST + ar);
                    const float4 vc = ldsf4(ST + 528 + ar);
                    const float4 vd = ldsf4(ST + 1056 + ar);
                    fma4(s0, hk0[t], va); fma4(s0, gk0[t], vb);
                    fma4(s1, hk1[t], va); fma4(s1, gk1[t], vb);
                    fma4(d0, hk0[t], vc); fma4(d0, gk0[t], vd);
                    fma4(d1, hk1[t], vc); fma4(d1, gk1[t], vd);
                }
                const int ri = 2 * (n - ((R0 >> 2) - 1));
                stsf4(SD + ri * 24 + fc, s0); stsf4(SD + (ri + 1) * 24 + fc, s1);
                stsf4(SD + 864 + ri * 24 + fc, d0); stsf4(SD + 864 + (ri + 1) * 24 + fc, d1);
            }
        }
        __syncthreads();
        float rA0[9];
        {
            const int a0r0 = (R0 >> 1) - 2, a0c0 = (W0 >> 1) - 4;
#pragma unroll
            for (int k = 0; k < 9; ++k) {
                const int e = tid + BLK * k;
                if (e < 4320) {
                    const int q = e / 1440, rm = e - q * 1440;
                    const float* p = (q == 0) ? psd0 : (q == 1) ? pds0 : pdd0;
                    rA0[k] = ldrc(p, a0r0 + rm / 40, a0c0 + rm % 40, 512);
                }
            }
        }
        {
            const int i1r0 = (R0 >> 1) - 2;
            const int riLo = max(0, -i1r0), riHi = min(36, 512 - i1r0);
            const int pcLo = max(0, -((W0 >> 2) - 1)), pcHi = min(18, 256 - ((W0 >> 2) - 1));
            const int np = pcHi - pcLo, cnt = (riHi - riLo) * np;
            for (int e = tid; e < cnt; e += BLK) {
                const int ri = riLo + e / np, pc = pcLo + e % np;
                float o0 = 0.f, o1 = 0.f;
#pragma unroll
                for (int t = 0; t < TAPS; ++t) {
                    const float sv = SD[ri * 24 + pc + 1 + t];
                    const float dv = SD[864 + ri * 24 + pc + 1 + t];
                    o0 += hk0[t] * sv + gk0[t] * dv;
                    o1 += hk1[t] * sv + gk1[t] * dv;
                }
                I1[ri * 40 + 2 * pc + 2] = o0; I1[ri * 40 + 2 * pc + 3] = o1;
            }
        }
#pragma unroll
        for (int k = 0; k < 9; ++k) {
            const int e = tid + BLK * k;
            if (e < 4320) ST[e] = rA0[k];
        }
        __syncthreads();
        {
            const int i1r0 = (R0 >> 1) - 2, c0t = (W0 >> 1) - 2;
            const int riLo = max(0, -i1r0), riHi = min(36, 512 - i1r0), nr = riHi - riLo;
            const int zL = max(0, -c0t), eR = min(36, 512 - c0t);
            if (zL > 0) for (int e = tid; e < nr * zL; e += BLK) {
                const int ri = riLo + e / zL, x = e % zL + 2, zx = zL + 2;
                I1[ri * 40 + x] = 2.f * I1[ri * 40 + zx] - I1[ri * 40 + 2 * zx - x];
            }
            if (eR < 36) { const int nv = 36 - eR;
                for (int e = tid; e < nr * nv; e += BLK) {
                    const int ri = riLo + e / nv, x = eR + e % nv + 2, ex = eR + 1;
                    I1[ri * 40 + x] = 2.f * I1[ri * 40 + ex] - I1[ri * 40 + 2 * ex - x];
                } }
        }
        __syncthreads();
        {
            const int i1r0 = (R0 >> 1) - 2;
            const int zT = max(0, -i1r0), eB = min(36, 512 - i1r0);
            if (zT > 0) for (int e = tid; e < zT * 36; e += BLK) {
                const int vr = e / 36, c = e % 36 + 2;
                I1[vr * 40 + c] = 2.f * I1[zT * 40 + c] - I1[(2 * zT - vr) * 40 + c];
            }
            if (eB < 36) { const int nv = 36 - eB;
                for (int e = tid; e < nv * 36; e += BLK) {
                    const int vr = eB + e / 36, c = e % 36 + 2;
                    I1[vr * 40 + c] = 2.f * I1[(eB - 1) * 40 + c] - I1[(2 * (eB - 1) - vr) * 40 + c];
                } }
        }
        __syncthreads();
    }

    // ================= common LEVEL 0 =================
    // vert0: row-pair items -> S0 [64][40] @SD, D0 @SD+2560 (160 items)
    if (tid < 160) {
        const int ip = tid / 10, fc = (tid - ip * 10) * 4;
        float4 sA0{0,0,0,0}, sA1{0,0,0,0}, dA0{0,0,0,0}, dA1{0,0,0,0};
        float4 sB0{0,0,0,0}, sB1{0,0,0,0}, dB0{0,0,0,0}, dB1{0,0,0,0};
#pragma unroll
        for (int r = 0; r < 6; ++r) {
            const int rr = (2 * ip + r) * 40 + fc;
            const float4 va = ldsf4(I1 + rr);
            const float4 vb = ldsf4(ST + rr);
            const float4 vc = ldsf4(ST + 1440 + rr);
            const float4 vd = ldsf4(ST + 2880 + rr);
            if (r < 5) {
                fma4(sA0, hk0[r], va); fma4(sA0, gk0[r], vb);
                fma4(sA1, hk1[r], va); fma4(sA1, gk1[r], vb);
                fma4(dA0, hk0[r], vc); fma4(dA0, gk0[r], vd);
                fma4(dA1, hk1[r], vc); fma4(dA1, gk1[r], vd);
            }
            if (r >= 1) {
                const int t = r - 1;
                fma4(sB0, hk0[t], va); fma4(sB0, gk0[t], vb);
                fma4(sB1, hk1[t], va); fma4(sB1, gk1[t], vb);
                fma4(dB0, hk0[t], vc); fma4(dB0, gk0[t], vd);
                fma4(dB1, hk1[t], vc); fma4(dB1, gk1[t], vd);
            }
        }
        const int r4 = 4 * ip;
        stsf4(SD + (r4    ) * 40 + fc, sA0); stsf4(SD + (r4 + 1) * 40 + fc, sA1);
        stsf4(SD + (r4 + 2) * 40 + fc, sB0); stsf4(SD + (r4 + 3) * 40 + fc, sB1);
        stsf4(SD + 2560 + (r4    ) * 40 + fc, dA0); stsf4(SD + 2560 + (r4 + 1) * 40 + fc, dA1);
        stsf4(SD + 2560 + (r4 + 2) * 40 + fc, dB0); stsf4(SD + 2560 + (r4 + 3) * 40 + fc, dB1);
    }
    __syncthreads();
    // horiz0: 1 item/thread (512 items)
    {
        const int ri = tid >> 3, u = tid & 7;
        float sv[12], dv[12];
        *reinterpret_cast<float4*>(&sv[0]) = ldsf4(SD + ri * 40 + 4 * u);
        *reinterpret_cast<float4*>(&sv[4]) = ldsf4(SD + ri * 40 + 4 * u + 4);
        *reinterpret_cast<float4*>(&sv[8]) = ldsf4(SD + ri * 40 + 4 * u + 8);
        *reinterpret_cast<float4*>(&dv[0]) = ldsf4(SD + 2560 + ri * 40 + 4 * u);
        *reinterpret_cast<float4*>(&dv[4]) = ldsf4(SD + 2560 + ri * 40 + 4 * u + 4);
        *reinterpret_cast<float4*>(&dv[8]) = ldsf4(SD + 2560 + ri * 40 + 4 * u + 8);
        float o[8];
#pragma unroll
        for (int j = 0; j < 4; ++j) {
            float o0 = 0.f, o1 = 0.f;
#pragma unroll
            for (int t = 0; t < TAPS; ++t) {
                o0 += hk0[t] * sv[2 + j + t] + gk0[t] * dv[2 + j + t];
                o1 += hk1[t] * sv[2 + j + t] + gk1[t] * dv[2 + j + t];
            }
            o[2 * j] = o0; o[2 * j + 1] = o1;
        }
        float* dst = out + ((size_t)(b * 1024 + R0 + ri)) * 1024 + W0 + 8 * u;
        *reinterpret_cast<float4*>(dst)     = make_float4(o[0], o[1], o[2], o[3]);
        *reinterpret_cast<float4*>(dst + 4) = make_float4(o[4], o[5], o[6], o[7]);
    }
}

extern "C" void kernel_launch(void* const* d_in, const int* in_sizes, int n_in,
                              void* d_out, int out_size, void* d_ws, size_t ws_size,
                              hipStream_t stream) {
    const float* ss  = (const float*)d_in[0];
    const float* sd0 = (const float*)d_in[1];
    const float* sd1 = (const float*)d_in[2];
    const float* sd2 = (const float*)d_in[3];
    const float* ds0 = (const float*)d_in[4];
    const float* ds1 = (const float*)d_in[5];
    const float* ds2 = (const float*)d_in[6];
    const float* dd0 = (const float*)d_in[7];
    const float* dd1 = (const float*)d_in[8];
    const float* dd2 = (const float*)d_in[9];
    const float* h = (const float*)d_in[10];
    const float* g = (const float*)d_in[11];
    float* out = (float*)d_out;

    idwt3<<<2048, BLK, SM_FLOATS * 4, stream>>>(
        ss, sd0, sd1, sd2, ds0, ds1, ds2, dd0, dd1, dd2, h, g, out);
}

// Round 20
// 32.419 us; speedup vs baseline: 1.0162x; 1.0162x over previous
//
#include <hip/hip_runtime.h>

#define TAPS 5
#define BLK 512

// antireflect fetch from a global plane
__device__ __forceinline__ float ldcg(const float* __restrict__ row, int j, int N) {
    if ((unsigned)j < (unsigned)N) return row[j];
    const int e = (j < 0) ? 0 : N - 1;
    const int r = (j < 0) ? -j : 2 * (N - 1) - j;
    return 2.f * row[e] - row[r];
}
__device__ __forceinline__ float ldrc(const float* __restrict__ p, int m, int j, int N) {
    if ((unsigned)m < (unsigned)N) return ldcg(p + (size_t)m * N, j, N);
    const int e = (m < 0) ? 0 : N - 1;
    const int r = (m < 0) ? -m : 2 * (N - 1) - m;
    return 2.f * ldcg(p + (size_t)e * N, j, N) - ldcg(p + (size_t)r * N, j, N);
}
__device__ __forceinline__ void fma4(float4& a, float c, const float4& v) {
    a.x += c * v.x; a.y += c * v.y; a.z += c * v.z; a.w += c * v.w;
}
__device__ __forceinline__ float4 ldsf4(const float* p) { return *reinterpret_cast<const float4*>(p); }
__device__ __forceinline__ void stsf4(float* p, const float4& v) { *reinterpret_cast<float4*>(p) = v; }
__device__ __forceinline__ void gl_lds16(const float* g, float* l) {
    __builtin_amdgcn_global_load_lds(
        (const __attribute__((address_space(1))) void*)g,
        (__attribute__((address_space(3))) void*)l, 16, 0, 0);
}

// LDS floats: ST 0..4320 | SD 4320..6880 (2560) | I0 6880..7456 | I1 7456..8896
// 35.6 KB -> 4 blocks/CU (32 waves/CU, the max at 512 thr/blk)
#define OFF_SD 4320
#define OFF_I0 6880
#define OFF_I1 7456
#define SM_FLOATS 8896

__global__ __launch_bounds__(BLK)
void idwt3(const float* __restrict__ ss,
           const float* __restrict__ sd0, const float* __restrict__ sd1, const float* __restrict__ sd2,
           const float* __restrict__ ds0, const float* __restrict__ ds1, const float* __restrict__ ds2,
           const float* __restrict__ dd0, const float* __restrict__ dd1, const float* __restrict__ dd2,
           const float* __restrict__ h, const float* __restrict__ g_,
           float* __restrict__ out) {
    extern __shared__ float sm[];
    float* ST = sm;
    float* SD = sm + OFF_SD;
    float* I0 = sm + OFF_I0;   // [24][24], row0 = R0/4-4, col0 = W0/4-4
    float* I1 = sm + OFF_I1;   // [36][40], row0 = R0/2-2, x-grid col0 = W0/2-4

    const int hw = blockIdx.x;
    const int lb = (hw & 7) * 256 + (hw >> 3);   // XCD swizzle
    const int b  = lb >> 8;
    const int tile = lb & 255;
    const int tr = tile >> 4, tc = tile & 15;
    const int R0 = tr * 64, W0 = tc * 64;
    const int tid = threadIdx.x;

    float hk0[TAPS], hk1[TAPS], gk0[TAPS], gk1[TAPS];
#pragma unroll
    for (int t = 0; t < TAPS; ++t) {
        hk0[t] = h[8 - 2 * t];  hk1[t] = h[9 - 2 * t];
        gk0[t] = g_[8 - 2 * t]; gk1[t] = g_[9 - 2 * t];
    }

    const float* pss  = ss  + (size_t)b * 16384;
    const float* psd2 = sd2 + (size_t)b * 16384;
    const float* pds2 = ds2 + (size_t)b * 16384;
    const float* pdd2 = dd2 + (size_t)b * 16384;
    const float* psd1 = sd1 + (size_t)b * 65536;
    const float* pds1 = ds1 + (size_t)b * 65536;
    const float* pdd1 = dd1 + (size_t)b * 65536;
    const float* psd0 = sd0 + (size_t)b * 262144;
    const float* pds0 = ds0 + (size_t)b * 262144;
    const float* pdd0 = dd0 + (size_t)b * 262144;

    const bool inner = (tr >= 1) && (tr <= 14) && (tc >= 1) && (tc <= 14);

    if (inner) {
        // ======== FAST PATH ========
        if (tid < 256) {   // A2: 4 planes [16][16]
            const int r0g = 8 * tr - 4, c0g = 8 * tc - 4;
            const int q = tid >> 6, rm = tid & 63, r = rm >> 2, c4 = rm & 3;
            const float* p = (q == 0) ? pss : (q == 1) ? psd2 : (q == 2) ? pds2 : pdd2;
            gl_lds16(p + (r0g + r) * 128 + c0g + 4 * c4, ST + 4 * tid);
        }
        __syncthreads();
        // vert2 -> S2 [24][16] @SD, D2 @SD+384
        if (tid < 48) {
            const int i = tid >> 2, fc = (tid & 3) * 4;
            float4 s0{0,0,0,0}, s1{0,0,0,0}, d0{0,0,0,0}, d1{0,0,0,0};
#pragma unroll
            for (int t = 0; t < TAPS; ++t) {
                const int rr = (i + t) * 16 + fc;
                const float4 va = ldsf4(ST + rr);
                const float4 vb = ldsf4(ST + 256 + rr);
                const float4 vc = ldsf4(ST + 512 + rr);
                const float4 vd = ldsf4(ST + 768 + rr);
                fma4(s0, hk0[t], va); fma4(s0, gk0[t], vb);
                fma4(s1, hk1[t], va); fma4(s1, gk1[t], vb);
                fma4(d0, hk0[t], vc); fma4(d0, gk0[t], vd);
                fma4(d1, hk1[t], vc); fma4(d1, gk1[t], vd);
            }
            const int ri = 2 * i;
            stsf4(SD + ri * 16 + fc, s0); stsf4(SD + (ri + 1) * 16 + fc, s1);
            stsf4(SD + 384 + ri * 16 + fc, d0); stsf4(SD + 384 + (ri + 1) * 16 + fc, d1);
        }
        __syncthreads();
        if (tid < 396) {   // issue A1: 3 planes [22][24] (overlaps horiz2)
            const int a1r0 = 16 * tr - 3, a1c0 = 16 * tc - 4;
            const int q = tid / 132, rm = tid - q * 132, r = rm / 6, c4 = rm - r * 6;
            const float* p = (q == 0) ? psd1 : (q == 1) ? pds1 : pdd1;
            gl_lds16(p + (a1r0 + r) * 256 + a1c0 + 4 * c4, ST + 4 * tid);
        }
        // horiz2 -> I0 [24][24] (288 items)
        if (tid < 288) {
            const int ri = tid / 12, pc = tid - ri * 12;
            float o0 = 0.f, o1 = 0.f;
#pragma unroll
            for (int t = 0; t < TAPS; ++t) {
                const float sv = SD[ri * 16 + pc + t];
                const float dv = SD[384 + ri * 16 + pc + t];
                o0 += hk0[t] * sv + gk0[t] * dv;
                o1 += hk1[t] * sv + gk1[t] * dv;
            }
            I0[ri * 24 + 2 * pc] = o0; I0[ri * 24 + 2 * pc + 1] = o1;
        }
        __syncthreads();   // drains A1 loads
        // vert1 -> S1 [36][24] @SD, D1 @SD+864 (108 items)
        if (tid < 108) {
            const int i = tid / 6, fc = (tid - i * 6) * 4;
            float4 s0{0,0,0,0}, s1{0,0,0,0}, d0{0,0,0,0}, d1{0,0,0,0};
#pragma unroll
            for (int t = 0; t < TAPS; ++t) {
                const float4 va = ldsf4(I0 + (i + t + 1) * 24 + fc);
                const int ar = (i + t) * 24 + fc;
                const float4 vb = ldsf4(ST + ar);
                const float4 vc = ldsf4(ST + 528 + ar);
                const float4 vd = ldsf4(ST + 1056 + ar);
                fma4(s0, hk0[t], va); fma4(s0, gk0[t], vb);
                fma4(s1, hk1[t], va); fma4(s1, gk1[t], vb);
                fma4(d0, hk0[t], vc); fma4(d0, gk0[t], vd);
                fma4(d1, hk1[t], vc); fma4(d1, gk1[t], vd);
            }
            const int ri = 2 * i;
            stsf4(SD + ri * 24 + fc, s0); stsf4(SD + (ri + 1) * 24 + fc, s1);
            stsf4(SD + 864 + ri * 24 + fc, d0); stsf4(SD + 864 + (ri + 1) * 24 + fc, d1);
        }
        __syncthreads();
        {   // issue A0: 3 planes [36][40] (overlaps horiz1)
            const int a0r0 = 32 * tr - 2, a0c0 = 32 * tc - 4;
#pragma unroll
            for (int k = 0; k < 3; ++k) {
                const int e = tid + BLK * k;
                if (e < 1080) {
                    const int q = e / 360, rm = e - q * 360, r = rm / 10, c4 = rm - r * 10;
                    const float* p = (q == 0) ? psd0 : (q == 1) ? pds0 : pdd0;
                    gl_lds16(p + (a0r0 + r) * 512 + a0c0 + 4 * c4, ST + 4 * e);
                }
            }
        }
        // horiz1 -> I1 x-grid (648 items)
#pragma unroll
        for (int k = 0; k < 2; ++k) {
            const int e = tid + BLK * k;
            if (e < 648) {
                const int ri = e / 18, pc = e - ri * 18;
                float o0 = 0.f, o1 = 0.f;
#pragma unroll
                for (int t = 0; t < TAPS; ++t) {
                    const float sv = SD[ri * 24 + pc + 1 + t];
                    const float dv = SD[864 + ri * 24 + pc + 1 + t];
                    o0 += hk0[t] * sv + gk0[t] * dv;
                    o1 += hk1[t] * sv + gk1[t] * dv;
                }
                I1[ri * 40 + 2 * pc + 2] = o0; I1[ri * 40 + 2 * pc + 3] = o1;
            }
        }
        __syncthreads();   // drains A0 loads
    } else {
        // ======== EDGE PATH ========
        {
            const int r0g = (R0 >> 3) - 4, c0g = (W0 >> 3) - 4;
            for (int e = tid; e < 1024; e += BLK) {
                const int q = e >> 8, rm = e & 255;
                const float* p = (q == 0) ? pss : (q == 1) ? psd2 : (q == 2) ? pds2 : pdd2;
                ST[e] = ldrc(p, r0g + (rm >> 4), c0g + (rm & 15), 128);
            }
        }
        __syncthreads();
        {
            const int lo = max((R0 >> 3) - 2, 0), hi = min((R0 >> 3) + 10, 128);
            const int a2r0 = (R0 >> 3) - 4;
            const int cnt = (hi - lo) * 4;
            for (int e = tid; e < cnt; e += BLK) {
                const int i = e >> 2, fc = (e & 3) * 4;
                const int n = lo + i;
                float4 s0{0,0,0,0}, s1{0,0,0,0}, d0{0,0,0,0}, d1{0,0,0,0};
#pragma unroll
                for (int t = 0; t < TAPS; ++t) {
                    const int rr = (n - 2 + t - a2r0) * 16 + fc;
                    const float4 va = ldsf4(ST + rr);
                    const float4 vb = ldsf4(ST + 256 + rr);
                    const float4 vc = ldsf4(ST + 512 + rr);
                    const float4 vd = ldsf4(ST + 768 + rr);
                    fma4(s0, hk0[t], va); fma4(s0, gk0[t], vb);
                    fma4(s1, hk1[t], va); fma4(s1, gk1[t], vb);
                    fma4(d0, hk0[t], vc); fma4(d0, gk0[t], vd);
                    fma4(d1, hk1[t], vc); fma4(d1, gk1[t], vd);
                }
                const int ri = 2 * (n - ((R0 >> 3) - 2));
                stsf4(SD + ri * 16 + fc, s0); stsf4(SD + (ri + 1) * 16 + fc, s1);
                stsf4(SD + 384 + ri * 16 + fc, d0); stsf4(SD + 384 + (ri + 1) * 16 + fc, d1);
            }
        }
        __syncthreads();
        float rA1[4];
        {
            const int a1r0 = (R0 >> 2) - 3, a1c0 = (W0 >> 2) - 4;
#pragma unroll
            for (int k = 0; k < 4; ++k) {
                const int e = tid + BLK * k;
                if (e < 1584) {
                    const int q = e / 528, rm = e - q * 528;
                    const float* p = (q == 0) ? psd1 : (q == 1) ? pds1 : pdd1;
                    rA1[k] = ldrc(p, a1r0 + rm / 24, a1c0 + rm % 24, 256);
                }
            }
        }
        {
            const int i0r0 = (R0 >> 2) - 4;
            const int riLo = max(0, -i0r0), riHi = min(24, 256 - i0r0);
            const int pcLo = max(0, -((W0 >> 3) - 2)), pcHi = min(12, 128 - ((W0 >> 3) - 2));
            const int np = pcHi - pcLo, cnt = (riHi - riLo) * np;
            for (int e = tid; e < cnt; e += BLK) {
                const int ri = riLo + e / np, pc = pcLo + e % np;
                float o0 = 0.f, o1 = 0.f;
#pragma unroll
                for (int t = 0; t < TAPS; ++t) {
                    const float sv = SD[ri * 16 + pc + t];
                    const float dv = SD[384 + ri * 16 + pc + t];
                    o0 += hk0[t] * sv + gk0[t] * dv;
                    o1 += hk1[t] * sv + gk1[t] * dv;
                }
                I0[ri * 24 + 2 * pc] = o0; I0[ri * 24 + 2 * pc + 1] = o1;
            }
        }
#pragma unroll
        for (int k = 0; k < 4; ++k) { const int e = tid + BLK * k; if (e < 1584) ST[e] = rA1[k]; }
        __syncthreads();
        {
            const int i0r0 = (R0 >> 2) - 4, i0c0 = (W0 >> 2) - 4;
            const int riLo = max(0, -i0r0), riHi = min(24, 256 - i0r0), nr = riHi - riLo;
            const int zL = max(0, -i0c0), eR = min(24, 256 - i0c0);
            if (zL > 0) for (int e = tid; e < nr * zL; e += BLK) {
                const int ri = riLo + e / zL, vc = e % zL;
                I0[ri * 24 + vc] = 2.f * I0[ri * 24 + zL] - I0[ri * 24 + 2 * zL - vc];
            }
            if (eR < 24) { const int nv = 24 - eR;
                for (int e = tid; e < nr * nv; e += BLK) {
                    const int ri = riLo + e / nv, vc = eR + e % nv;
                    I0[ri * 24 + vc] = 2.f * I0[ri * 24 + eR - 1] - I0[ri * 24 + 2 * (eR - 1) - vc];
                } }
        }
        __syncthreads();
        {
            const int i0r0 = (R0 >> 2) - 4;
            const int zT = max(0, -i0r0), eB = min(24, 256 - i0r0);
            if (zT > 0) for (int e = tid; e < zT * 24; e += BLK) {
                const int vr = e / 24, c = e % 24;
                I0[vr * 24 + c] = 2.f * I0[zT * 24 + c] - I0[(2 * zT - vr) * 24 + c];
            }
            if (eB < 24) { const int nv = 24 - eB;
                for (int e = tid; e < nv * 24; e += BLK) {
                    const int vr = eB + e / 24, c = e % 24;
                    I0[vr * 24 + c] = 2.f * I0[(eB - 1) * 24 + c] - I0[(2 * (eB - 1) - vr) * 24 + c];
                } }
        }
        __syncthreads();
        {
            const int lo = max((R0 >> 2) - 1, 0), hi = min((R0 >> 2) + 17, 256);
            const int i0r0 = (R0 >> 2) - 4, a1r0 = (R0 >> 2) - 3;
            const int cnt = (hi - lo) * 6;
            for (int e = tid; e < cnt; e += BLK) {
                const int i = e / 6, fc = (e % 6) * 4;
                const int n = lo + i;
                float4 s0{0,0,0,0}, s1{0,0,0,0}, d0{0,0,0,0}, d1{0,0,0,0};
#pragma unroll
                for (int t = 0; t < TAPS; ++t) {
                    const int m = n - 2 + t;
                    const float4 va = ldsf4(I0 + (m - i0r0) * 24 + fc);
                    const int ar = (m - a1r0) * 24 + fc;
                    const float4 vb = ldsf4(ST + ar);
                    const float4 vc = ldsf4(ST + 528 + ar);
                    const float4 vd = ldsf4(ST + 1056 + ar);
                    fma4(s0, hk0[t], va); fma4(s0, gk0[t], vb);
                    fma4(s1, hk1[t], va); fma4(s1, gk1[t], vb);
                    fma4(d0, hk0[t], vc); fma4(d0, gk0[t], vd);
                    fma4(d1, hk1[t], vc); fma4(d1, gk1[t], vd);
                }
                const int ri = 2 * (n - ((R0 >> 2) - 1));
                stsf4(SD + ri * 24 + fc, s0); stsf4(SD + (ri + 1) * 24 + fc, s1);
                stsf4(SD + 864 + ri * 24 + fc, d0); stsf4(SD + 864 + (ri + 1) * 24 + fc, d1);
            }
        }
        __syncthreads();
        float rA0[9];
        {
            const int a0r0 = (R0 >> 1) - 2, a0c0 = (W0 >> 1) - 4;
#pragma unroll
            for (int k = 0; k < 9; ++k) {
                const int e = tid + BLK * k;
                if (e < 4320) {
                    const int q = e / 1440, rm = e - q * 1440;
                    const float* p = (q == 0) ? psd0 : (q == 1) ? pds0 : pdd0;
                    rA0[k] = ldrc(p, a0r0 + rm / 40, a0c0 + rm % 40, 512);
                }
            }
        }
        {
            const int i1r0 = (R0 >> 1) - 2;
            const int riLo = max(0, -i1r0), riHi = min(36, 512 - i1r0);
            const int pcLo = max(0, -((W0 >> 2) - 1)), pcHi = min(18, 256 - ((W0 >> 2) - 1));
            const int np = pcHi - pcLo, cnt = (riHi - riLo) * np;
            for (int e = tid; e < cnt; e += BLK) {
                const int ri = riLo + e / np, pc = pcLo + e % np;
                float o0 = 0.f, o1 = 0.f;
#pragma unroll
                for (int t = 0; t < TAPS; ++t) {
                    const float sv = SD[ri * 24 + pc + 1 + t];
                    const float dv = SD[864 + ri * 24 + pc + 1 + t];
                    o0 += hk0[t] * sv + gk0[t] * dv;
                    o1 += hk1[t] * sv + gk1[t] * dv;
                }
                I1[ri * 40 + 2 * pc + 2] = o0; I1[ri * 40 + 2 * pc + 3] = o1;
            }
        }
#pragma unroll
        for (int k = 0; k < 9; ++k) {
            const int e = tid + BLK * k;
            if (e < 4320) ST[e] = rA0[k];
        }
        __syncthreads();
        {
            const int i1r0 = (R0 >> 1) - 2, c0t = (W0 >> 1) - 2;
            const int riLo = max(0, -i1r0), riHi = min(36, 512 - i1r0), nr = riHi - riLo;
            const int zL = max(0, -c0t), eR = min(36, 512 - c0t);
            if (zL > 0) for (int e = tid; e < nr * zL; e += BLK) {
                const int ri = riLo + e / zL, x = e % zL + 2, zx = zL + 2;
                I1[ri * 40 + x] = 2.f * I1[ri * 40 + zx] - I1[ri * 40 + 2 * zx - x];
            }
            if (eR < 36) { const int nv = 36 - eR;
                for (int e = tid; e < nr * nv; e += BLK) {
                    const int ri = riLo + e / nv, x = eR + e % nv + 2, ex = eR + 1;
                    I1[ri * 40 + x] = 2.f * I1[ri * 40 + ex] - I1[ri * 40 + 2 * ex - x];
                } }
        }
        __syncthreads();
        {
            const int i1r0 = (R0 >> 1) - 2;
            const int zT = max(0, -i1r0), eB = min(36, 512 - i1r0);
            if (zT > 0) for (int e = tid; e < zT * 36; e += BLK) {
                const int vr = e / 36, c = e % 36 + 2;
                I1[vr * 40 + c] = 2.f * I1[zT * 40 + c] - I1[(2 * zT - vr) * 40 + c];
            }
            if (eB < 36) { const int nv = 36 - eB;
                for (int e = tid; e < nv * 36; e += BLK) {
                    const int vr = eB + e / 36, c = e % 36 + 2;
                    I1[vr * 40 + c] = 2.f * I1[(eB - 1) * 40 + c] - I1[(2 * (eB - 1) - vr) * 40 + c];
                } }
        }
        __syncthreads();
    }

    // ================= common LEVEL 0: two 32-row halves through SD (2560 floats) =================
    for (int hf = 0; hf < 2; ++hf) {
        // vert0 half: 160 items (16 row-pairs x 10 f4 cols) -> S0h @SD, D0h @SD+1280
        if (tid < 160) {
            const int il = tid / 10, fc = (tid - il * 10) * 4;
            const int i = 16 * hf + il;          // global row-pair index 0..31
            float4 s0{0,0,0,0}, s1{0,0,0,0}, d0{0,0,0,0}, d1{0,0,0,0};
#pragma unroll
            for (int t = 0; t < TAPS; ++t) {
                const int rr = (i + t) * 40 + fc;
                const float4 va = ldsf4(I1 + rr);
                const float4 vb = ldsf4(ST + rr);
                const float4 vc = ldsf4(ST + 1440 + rr);
                const float4 vd = ldsf4(ST + 2880 + rr);
                fma4(s0, hk0[t], va); fma4(s0, gk0[t], vb);
                fma4(s1, hk1[t], va); fma4(s1, gk1[t], vb);
                fma4(d0, hk0[t], vc); fma4(d0, gk0[t], vd);
                fma4(d1, hk1[t], vc); fma4(d1, gk1[t], vd);
            }
            const int ri = 2 * il;               // local SD row 0..31
            stsf4(SD + ri * 40 + fc, s0); stsf4(SD + (ri + 1) * 40 + fc, s1);
            stsf4(SD + 1280 + ri * 40 + fc, d0); stsf4(SD + 1280 + (ri + 1) * 40 + fc, d1);
        }
        __syncthreads();
        // horiz0 half: 256 items (32 rows x 8 col-chunks)
        if (tid < 256) {
            const int rl = tid >> 3, u = tid & 7;
            float sv[12], dv[12];
            *reinterpret_cast<float4*>(&sv[0]) = ldsf4(SD + rl * 40 + 4 * u);
            *reinterpret_cast<float4*>(&sv[4]) = ldsf4(SD + rl * 40 + 4 * u + 4);
            *reinterpret_cast<float4*>(&sv[8]) = ldsf4(SD + rl * 40 + 4 * u + 8);
            *reinterpret_cast<float4*>(&dv[0]) = ldsf4(SD + 1280 + rl * 40 + 4 * u);
            *reinterpret_cast<float4*>(&dv[4]) = ldsf4(SD + 1280 + rl * 40 + 4 * u + 4);
            *reinterpret_cast<float4*>(&dv[8]) = ldsf4(SD + 1280 + rl * 40 + 4 * u + 8);
            float o[8];
#pragma unroll
            for (int j = 0; j < 4; ++j) {
                float o0 = 0.f, o1 = 0.f;
#pragma unroll
                for (int t = 0; t < TAPS; ++t) {
                    o0 += hk0[t] * sv[2 + j + t] + gk0[t] * dv[2 + j + t];
                    o1 += hk1[t] * sv[2 + j + t] + gk1[t] * dv[2 + j + t];
                }
                o[2 * j] = o0; o[2 * j + 1] = o1;
            }
            float* dst = out + ((size_t)(b * 1024 + R0 + 32 * hf + rl)) * 1024 + W0 + 8 * u;
            *reinterpret_cast<float4*>(dst)     = make_float4(o[0], o[1], o[2], o[3]);
            *reinterpret_cast<float4*>(dst + 4) = make_float4(o[4], o[5], o[6], o[7]);
        }
        __syncthreads();
    }
}

extern "C" void kernel_launch(void* const* d_in, const int* in_sizes, int n_in,
                              void* d_out, int out_size, void* d_ws, size_t ws_size,
                              hipStream_t stream) {
    const float* ss  = (const float*)d_in[0];
    const float* sd0 = (const float*)d_in[1];
    const float* sd1 = (const float*)d_in[2];
    const float* sd2 = (const float*)d_in[3];
    const float* ds0 = (const float*)d_in[4];
    const float* ds1 = (const float*)d_in[5];
    const float* ds2 = (const float*)d_in[6];
    const float* dd0 = (const float*)d_in[7];
    const float* dd1 = (const float*)d_in[8];
    const float* dd2 = (const float*)d_in[9];
    const float* h = (const float*)d_in[10];
    const float* g = (const float*)d_in[11];
    float* out = (float*)d_out;

    idwt3<<<2048, BLK, SM_FLOATS * 4, stream>>>(
        ss, sd0, sd1, sd2, ds0, ds1, ds2, dd0, dd1, dd2, h, g, out);
}

// Round 21
// 30.875 us; speedup vs baseline: 1.0670x; 1.0500x over previous
//
#include <hip/hip_runtime.h>

#define TAPS 5
#define BLK 512

// antireflect fetch from a global plane
__device__ __forceinline__ float ldcg(const float* __restrict__ row, int j, int N) {
    if ((unsigned)j < (unsigned)N) return row[j];
    const int e = (j < 0) ? 0 : N - 1;
    const int r = (j < 0) ? -j : 2 * (N - 1) - j;
    return 2.f * row[e] - row[r];
}
__device__ __forceinline__ float ldrc(const float* __restrict__ p, int m, int j, int N) {
    if ((unsigned)m < (unsigned)N) return ldcg(p + (size_t)m * N, j, N);
    const int e = (m < 0) ? 0 : N - 1;
    const int r = (m < 0) ? -m : 2 * (N - 1) - m;
    return 2.f * ldcg(p + (size_t)e * N, j, N) - ldcg(p + (size_t)r * N, j, N);
}
__device__ __forceinline__ void fma4(float4& a, float c, const float4& v) {
    a.x += c * v.x; a.y += c * v.y; a.z += c * v.z; a.w += c * v.w;
}
__device__ __forceinline__ float4 ldsf4(const float* p) { return *reinterpret_cast<const float4*>(p); }
__device__ __forceinline__ void stsf4(float* p, const float4& v) { *reinterpret_cast<float4*>(p) = v; }
__device__ __forceinline__ void gl_lds16(const float* g, float* l) {
    __builtin_amdgcn_global_load_lds(
        (const __attribute__((address_space(1))) void*)g,
        (__attribute__((address_space(3))) void*)l, 16, 0, 0);
}

// LDS floats: ST 0..4320 | SD 4320..9440 | I0 9440..10016 | I1 10016..11456
#define OFF_SD 4320
#define OFF_I0 9440
#define OFF_I1 10016
#define SM_FLOATS 11456

// One block (512 threads) = one 64x64 output tile; 3 IDWT levels fused in LDS.
__global__ __launch_bounds__(BLK)
void idwt3(const float* __restrict__ ss,
           const float* __restrict__ sd0, const float* __restrict__ sd1, const float* __restrict__ sd2,
           const float* __restrict__ ds0, const float* __restrict__ ds1, const float* __restrict__ ds2,
           const float* __restrict__ dd0, const float* __restrict__ dd1, const float* __restrict__ dd2,
           const float* __restrict__ h, const float* __restrict__ g_,
           float* __restrict__ out) {
    extern __shared__ float sm[];
    float* ST = sm;
    float* SD = sm + OFF_SD;
    float* I0 = sm + OFF_I0;   // [24][24], row0 = R0/4-4, col0 = W0/4-4
    float* I1 = sm + OFF_I1;   // [36][40], row0 = R0/2-2, x-grid col0 = W0/2-4

    const int hw = blockIdx.x;
    const int lb = (hw & 7) * 256 + (hw >> 3);   // XCD swizzle: XCD i -> batch i
    const int b  = lb >> 8;
    const int tile = lb & 255;
    const int tr = tile >> 4, tc = tile & 15;
    const int R0 = tr * 64, W0 = tc * 64;
    const int tid = threadIdx.x;

    float hk0[TAPS], hk1[TAPS], gk0[TAPS], gk1[TAPS];
#pragma unroll
    for (int t = 0; t < TAPS; ++t) {
        hk0[t] = h[8 - 2 * t];  hk1[t] = h[9 - 2 * t];
        gk0[t] = g_[8 - 2 * t]; gk1[t] = g_[9 - 2 * t];
    }

    const float* pss  = ss  + (size_t)b * 16384;
    const float* psd2 = sd2 + (size_t)b * 16384;
    const float* pds2 = ds2 + (size_t)b * 16384;
    const float* pdd2 = dd2 + (size_t)b * 16384;
    const float* psd1 = sd1 + (size_t)b * 65536;
    const float* pds1 = ds1 + (size_t)b * 65536;
    const float* pdd1 = dd1 + (size_t)b * 65536;
    const float* psd0 = sd0 + (size_t)b * 262144;
    const float* pds0 = ds0 + (size_t)b * 262144;
    const float* pdd0 = dd0 + (size_t)b * 262144;

    const bool inner = (tr >= 1) && (tr <= 14) && (tc >= 1) && (tc <= 14);

    if (inner) {
        // ======== FAST PATH ========
        if (tid < 256) {   // A2: 4 planes [16][16]
            const int r0g = 8 * tr - 4, c0g = 8 * tc - 4;
            const int q = tid >> 6, rm = tid & 63, r = rm >> 2, c4 = rm & 3;
            const float* p = (q == 0) ? pss : (q == 1) ? psd2 : (q == 2) ? pds2 : pdd2;
            gl_lds16(p + (r0g + r) * 128 + c0g + 4 * c4, ST + 4 * tid);
        }
        __syncthreads();
        // vert2 -> S2 [24][16] @SD, D2 @SD+384
        if (tid < 48) {
            const int i = tid >> 2, fc = (tid & 3) * 4;
            float4 s0{0,0,0,0}, s1{0,0,0,0}, d0{0,0,0,0}, d1{0,0,0,0};
#pragma unroll
            for (int t = 0; t < TAPS; ++t) {
                const int rr = (i + t) * 16 + fc;
                const float4 va = ldsf4(ST + rr);
                const float4 vb = ldsf4(ST + 256 + rr);
                const float4 vc = ldsf4(ST + 512 + rr);
                const float4 vd = ldsf4(ST + 768 + rr);
                fma4(s0, hk0[t], va); fma4(s0, gk0[t], vb);
                fma4(s1, hk1[t], va); fma4(s1, gk1[t], vb);
                fma4(d0, hk0[t], vc); fma4(d0, gk0[t], vd);
                fma4(d1, hk1[t], vc); fma4(d1, gk1[t], vd);
            }
            const int ri = 2 * i;
            stsf4(SD + ri * 16 + fc, s0); stsf4(SD + (ri + 1) * 16 + fc, s1);
            stsf4(SD + 384 + ri * 16 + fc, d0); stsf4(SD + 384 + (ri + 1) * 16 + fc, d1);
        }
        __syncthreads();
        if (tid < 396) {   // issue A1: 3 planes [22][24] (overlaps horiz2)
            const int a1r0 = 16 * tr - 3, a1c0 = 16 * tc - 4;
            const int q = tid / 132, rm = tid - q * 132, r = rm / 6, c4 = rm - r * 6;
            const float* p = (q == 0) ? psd1 : (q == 1) ? pds1 : pdd1;
            gl_lds16(p + (a1r0 + r) * 256 + a1c0 + 4 * c4, ST + 4 * tid);
        }
        // horiz2 -> I0 [24][24] (288 items)
        if (tid < 288) {
            const int ri = tid / 12, pc = tid - ri * 12;
            float o0 = 0.f, o1 = 0.f;
#pragma unroll
            for (int t = 0; t < TAPS; ++t) {
                const float sv = SD[ri * 16 + pc + t];
                const float dv = SD[384 + ri * 16 + pc + t];
                o0 += hk0[t] * sv + gk0[t] * dv;
                o1 += hk1[t] * sv + gk1[t] * dv;
            }
            I0[ri * 24 + 2 * pc] = o0; I0[ri * 24 + 2 * pc + 1] = o1;
        }
        __syncthreads();   // drains A1 loads
        // vert1 -> S1 [36][24] @SD, D1 @SD+864 (108 items)
        if (tid < 108) {
            const int i = tid / 6, fc = (tid - i * 6) * 4;
            float4 s0{0,0,0,0}, s1{0,0,0,0}, d0{0,0,0,0}, d1{0,0,0,0};
#pragma unroll
            for (int t = 0; t < TAPS; ++t) {
                const float4 va = ldsf4(I0 + (i + t + 1) * 24 + fc);
                const int ar = (i + t) * 24 + fc;
                const float4 vb = ldsf4(ST + ar);
                const float4 vc = ldsf4(ST + 528 + ar);
                const float4 vd = ldsf4(ST + 1056 + ar);
                fma4(s0, hk0[t], va); fma4(s0, gk0[t], vb);
                fma4(s1, hk1[t], va); fma4(s1, gk1[t], vb);
                fma4(d0, hk0[t], vc); fma4(d0, gk0[t], vd);
                fma4(d1, hk1[t], vc); fma4(d1, gk1[t], vd);
            }
            const int ri = 2 * i;
            stsf4(SD + ri * 24 + fc, s0); stsf4(SD + (ri + 1) * 24 + fc, s1);
            stsf4(SD + 864 + ri * 24 + fc, d0); stsf4(SD + 864 + (ri + 1) * 24 + fc, d1);
        }
        __syncthreads();
        {   // issue A0: 3 planes [36][40] (overlaps horiz1)
            const int a0r0 = 32 * tr - 2, a0c0 = 32 * tc - 4;
#pragma unroll
            for (int k = 0; k < 3; ++k) {
                const int e = tid + BLK * k;
                if (e < 1080) {
                    const int q = e / 360, rm = e - q * 360, r = rm / 10, c4 = rm - r * 10;
                    const float* p = (q == 0) ? psd0 : (q == 1) ? pds0 : pdd0;
                    gl_lds16(p + (a0r0 + r) * 512 + a0c0 + 4 * c4, ST + 4 * e);
                }
            }
        }
        // horiz1 -> I1 x-grid (648 items)
#pragma unroll
        for (int k = 0; k < 2; ++k) {
            const int e = tid + BLK * k;
            if (e < 648) {
                const int ri = e / 18, pc = e - ri * 18;
                float o0 = 0.f, o1 = 0.f;
#pragma unroll
                for (int t = 0; t < TAPS; ++t) {
                    const float sv = SD[ri * 24 + pc + 1 + t];
                    const float dv = SD[864 + ri * 24 + pc + 1 + t];
                    o0 += hk0[t] * sv + gk0[t] * dv;
                    o1 += hk1[t] * sv + gk1[t] * dv;
                }
                I1[ri * 40 + 2 * pc + 2] = o0; I1[ri * 40 + 2 * pc + 3] = o1;
            }
        }
        __syncthreads();   // drains A0 loads
    } else {
        // ======== EDGE PATH ========
        {
            const int r0g = (R0 >> 3) - 4, c0g = (W0 >> 3) - 4;
            for (int e = tid; e < 1024; e += BLK) {
                const int q = e >> 8, rm = e & 255;
                const float* p = (q == 0) ? pss : (q == 1) ? psd2 : (q == 2) ? pds2 : pdd2;
                ST[e] = ldrc(p, r0g + (rm >> 4), c0g + (rm & 15), 128);
            }
        }
        __syncthreads();
        {
            const int lo = max((R0 >> 3) - 2, 0), hi = min((R0 >> 3) + 10, 128);
            const int a2r0 = (R0 >> 3) - 4;
            const int cnt = (hi - lo) * 4;
            for (int e = tid; e < cnt; e += BLK) {
                const int i = e >> 2, fc = (e & 3) * 4;
                const int n = lo + i;
                float4 s0{0,0,0,0}, s1{0,0,0,0}, d0{0,0,0,0}, d1{0,0,0,0};
#pragma unroll
                for (int t = 0; t < TAPS; ++t) {
                    const int rr = (n - 2 + t - a2r0) * 16 + fc;
                    const float4 va = ldsf4(ST + rr);
                    const float4 vb = ldsf4(ST + 256 + rr);
                    const float4 vc = ldsf4(ST + 512 + rr);
                    const float4 vd = ldsf4(ST + 768 + rr);
                    fma4(s0, hk0[t], va); fma4(s0, gk0[t], vb);
                    fma4(s1, hk1[t], va); fma4(s1, gk1[t], vb);
                    fma4(d0, hk0[t], vc); fma4(d0, gk0[t], vd);
                    fma4(d1, hk1[t], vc); fma4(d1, gk1[t], vd);
                }
                const int ri = 2 * (n - ((R0 >> 3) - 2));
                stsf4(SD + ri * 16 + fc, s0); stsf4(SD + (ri + 1) * 16 + fc, s1);
                stsf4(SD + 384 + ri * 16 + fc, d0); stsf4(SD + 384 + (ri + 1) * 16 + fc, d1);
            }
        }
        __syncthreads();
        float rA1[4];
        {
            const int a1r0 = (R0 >> 2) - 3, a1c0 = (W0 >> 2) - 4;
#pragma unroll
            for (int k = 0; k < 4; ++k) {
                const int e = tid + BLK * k;
                if (e < 1584) {
                    const int q = e / 528, rm = e - q * 528;
                    const float* p = (q == 0) ? psd1 : (q == 1) ? pds1 : pdd1;
                    rA1[k] = ldrc(p, a1r0 + rm / 24, a1c0 + rm % 24, 256);
                }
            }
        }
        {
            const int i0r0 = (R0 >> 2) - 4;
            const int riLo = max(0, -i0r0), riHi = min(24, 256 - i0r0);
            const int pcLo = max(0, -((W0 >> 3) - 2)), pcHi = min(12, 128 - ((W0 >> 3) - 2));
            const int np = pcHi - pcLo, cnt = (riHi - riLo) * np;
            for (int e = tid; e < cnt; e += BLK) {
                const int ri = riLo + e / np, pc = pcLo + e % np;
                float o0 = 0.f, o1 = 0.f;
#pragma unroll
                for (int t = 0; t < TAPS; ++t) {
                    const float sv = SD[ri * 16 + pc + t];
                    const float dv = SD[384 + ri * 16 + pc + t];
                    o0 += hk0[t] * sv + gk0[t] * dv;
                    o1 += hk1[t] * sv + gk1[t] * dv;
                }
                I0[ri * 24 + 2 * pc] = o0; I0[ri * 24 + 2 * pc + 1] = o1;
            }
        }
#pragma unroll
        for (int k = 0; k < 4; ++k) { const int e = tid + BLK * k; if (e < 1584) ST[e] = rA1[k]; }
        __syncthreads();
        {
            const int i0r0 = (R0 >> 2) - 4, i0c0 = (W0 >> 2) - 4;
            const int riLo = max(0, -i0r0), riHi = min(24, 256 - i0r0), nr = riHi - riLo;
            const int zL = max(0, -i0c0), eR = min(24, 256 - i0c0);
            if (zL > 0) for (int e = tid; e < nr * zL; e += BLK) {
                const int ri = riLo + e / zL, vc = e % zL;
                I0[ri * 24 + vc] = 2.f * I0[ri * 24 + zL] - I0[ri * 24 + 2 * zL - vc];
            }
            if (eR < 24) { const int nv = 24 - eR;
                for (int e = tid; e < nr * nv; e += BLK) {
                    const int ri = riLo + e / nv, vc = eR + e % nv;
                    I0[ri * 24 + vc] = 2.f * I0[ri * 24 + eR - 1] - I0[ri * 24 + 2 * (eR - 1) - vc];
                } }
        }
        __syncthreads();
        {
            const int i0r0 = (R0 >> 2) - 4;
            const int zT = max(0, -i0r0), eB = min(24, 256 - i0r0);
            if (zT > 0) for (int e = tid; e < zT * 24; e += BLK) {
                const int vr = e / 24, c = e % 24;
                I0[vr * 24 + c] = 2.f * I0[zT * 24 + c] - I0[(2 * zT - vr) * 24 + c];
            }
            if (eB < 24) { const int nv = 24 - eB;
                for (int e = tid; e < nv * 24; e += BLK) {
                    const int vr = eB + e / 24, c = e % 24;
                    I0[vr * 24 + c] = 2.f * I0[(eB - 1) * 24 + c] - I0[(2 * (eB - 1) - vr) * 24 + c];
                } }
        }
        __syncthreads();
        {
            const int lo = max((R0 >> 2) - 1, 0), hi = min((R0 >> 2) + 17, 256);
            const int i0r0 = (R0 >> 2) - 4, a1r0 = (R0 >> 2) - 3;
            const int cnt = (hi - lo) * 6;
            for (int e = tid; e < cnt; e += BLK) {
                const int i = e / 6, fc = (e % 6) * 4;
                const int n = lo + i;
                float4 s0{0,0,0,0}, s1{0,0,0,0}, d0{0,0,0,0}, d1{0,0,0,0};
#pragma unroll
                for (int t = 0; t < TAPS; ++t) {
                    const int m = n - 2 + t;
                    const float4 va = ldsf4(I0 + (m - i0r0) * 24 + fc);
                    const int ar = (m - a1r0) * 24 + fc;
                    const float4 vb = ldsf4(ST + ar);
                    const float4 vc = ldsf4(ST + 528 + ar);
                    const float4 vd = ldsf4(ST + 1056 + ar);
                    fma4(s0, hk0[t], va); fma4(s0, gk0[t], vb);
                    fma4(s1, hk1[t], va); fma4(s1, gk1[t], vb);
                    fma4(d0, hk0[t], vc); fma4(d0, gk0[t], vd);
                    fma4(d1, hk1[t], vc); fma4(d1, gk1[t], vd);
                }
                const int ri = 2 * (n - ((R0 >> 2) - 1));
                stsf4(SD + ri * 24 + fc, s0); stsf4(SD + (ri + 1) * 24 + fc, s1);
                stsf4(SD + 864 + ri * 24 + fc, d0); stsf4(SD + 864 + (ri + 1) * 24 + fc, d1);
            }
        }
        __syncthreads();
        float rA0[9];
        {
            const int a0r0 = (R0 >> 1) - 2, a0c0 = (W0 >> 1) - 4;
#pragma unroll
            for (int k = 0; k < 9; ++k) {
                const int e = tid + BLK * k;
                if (e < 4320) {
                    const int q = e / 1440, rm = e - q * 1440;
                    const float* p = (q == 0) ? psd0 : (q == 1) ? pds0 : pdd0;
                    rA0[k] = ldrc(p, a0r0 + rm / 40, a0c0 + rm % 40, 512);
                }
            }
        }
        {
            const int i1r0 = (R0 >> 1) - 2;
            const int riLo = max(0, -i1r0), riHi = min(36, 512 - i1r0);
            const int pcLo = max(0, -((W0 >> 2) - 1)), pcHi = min(18, 256 - ((W0 >> 2) - 1));
            const int np = pcHi - pcLo, cnt = (riHi - riLo) * np;
            for (int e = tid; e < cnt; e += BLK) {
                const int ri = riLo + e / np, pc = pcLo + e % np;
                float o0 = 0.f, o1 = 0.f;
#pragma unroll
                for (int t = 0; t < TAPS; ++t) {
                    const float sv = SD[ri * 24 + pc + 1 + t];
                    const float dv = SD[864 + ri * 24 + pc + 1 + t];
                    o0 += hk0[t] * sv + gk0[t] * dv;
                    o1 += hk1[t] * sv + gk1[t] * dv;
                }
                I1[ri * 40 + 2 * pc + 2] = o0; I1[ri * 40 + 2 * pc + 3] = o1;
            }
        }
#pragma unroll
        for (int k = 0; k < 9; ++k) {
            const int e = tid + BLK * k;
            if (e < 4320) ST[e] = rA0[k];
        }
        __syncthreads();
        {
            const int i1r0 = (R0 >> 1) - 2, c0t = (W0 >> 1) - 2;
            const int riLo = max(0, -i1r0), riHi = min(36, 512 - i1r0), nr = riHi - riLo;
            const int zL = max(0, -c0t), eR = min(36, 512 - c0t);
            if (zL > 0) for (int e = tid; e < nr * zL; e += BLK) {
                const int ri = riLo + e / zL, x = e % zL + 2, zx = zL + 2;
                I1[ri * 40 + x] = 2.f * I1[ri * 40 + zx] - I1[ri * 40 + 2 * zx - x];
            }
            if (eR < 36) { const int nv = 36 - eR;
                for (int e = tid; e < nr * nv; e += BLK) {
                    const int ri = riLo + e / nv, x = eR + e % nv + 2, ex = eR + 1;
                    I1[ri * 40 + x] = 2.f * I1[ri * 40 + ex] - I1[ri * 40 + 2 * ex - x];
                } }
        }
        __syncthreads();
        {
            const int i1r0 = (R0 >> 1) - 2;
            const int zT = max(0, -i1r0), eB = min(36, 512 - i1r0);
            if (zT > 0) for (int e = tid; e < zT * 36; e += BLK) {
                const int vr = e / 36, c = e % 36 + 2;
                I1[vr * 40 + c] = 2.f * I1[zT * 40 + c] - I1[(2 * zT - vr) * 40 + c];
            }
            if (eB < 36) { const int nv = 36 - eB;
                for (int e = tid; e < nv * 36; e += BLK) {
                    const int vr = eB + e / 36, c = e % 36 + 2;
                    I1[vr * 40 + c] = 2.f * I1[(eB - 1) * 40 + c] - I1[(2 * (eB - 1) - vr) * 40 + c];
                } }
        }
        __syncthreads();
    }

    // ================= common LEVEL 0 =================
    // vert0 -> S0 [64][40] @SD, D0 @SD+2560 (320 items)
    if (tid < 320) {
        const int i = tid / 10, fc = (tid - i * 10) * 4;
        float4 s0{0,0,0,0}, s1{0,0,0,0}, d0{0,0,0,0}, d1{0,0,0,0};
#pragma unroll
        for (int t = 0; t < TAPS; ++t) {
            const int rr = (i + t) * 40 + fc;
            const float4 va = ldsf4(I1 + rr);
            const float4 vb = ldsf4(ST + rr);
            const float4 vc = ldsf4(ST + 1440 + rr);
            const float4 vd = ldsf4(ST + 2880 + rr);
            fma4(s0, hk0[t], va); fma4(s0, gk0[t], vb);
            fma4(s1, hk1[t], va); fma4(s1, gk1[t], vb);
            fma4(d0, hk0[t], vc); fma4(d0, gk0[t], vd);
            fma4(d1, hk1[t], vc); fma4(d1, gk1[t], vd);
        }
        const int ri = 2 * i;
        stsf4(SD + ri * 40 + fc, s0); stsf4(SD + (ri + 1) * 40 + fc, s1);
        stsf4(SD + 2560 + ri * 40 + fc, d0); stsf4(SD + 2560 + (ri + 1) * 40 + fc, d1);
    }
    __syncthreads();
    // horiz0: exactly 1 item per thread (512 items)
    {
        const int ri = tid >> 3, u = tid & 7;
        float sv[12], dv[12];
        *reinterpret_cast<float4*>(&sv[0]) = ldsf4(SD + ri * 40 + 4 * u);
        *reinterpret_cast<float4*>(&sv[4]) = ldsf4(SD + ri * 40 + 4 * u + 4);
        *reinterpret_cast<float4*>(&sv[8]) = ldsf4(SD + ri * 40 + 4 * u + 8);
        *reinterpret_cast<float4*>(&dv[0]) = ldsf4(SD + 2560 + ri * 40 + 4 * u);
        *reinterpret_cast<float4*>(&dv[4]) = ldsf4(SD + 2560 + ri * 40 + 4 * u + 4);
        *reinterpret_cast<float4*>(&dv[8]) = ldsf4(SD + 2560 + ri * 40 + 4 * u + 8);
        float o[8];
#pragma unroll
        for (int j = 0; j < 4; ++j) {
            float o0 = 0.f, o1 = 0.f;
#pragma unroll
            for (int t = 0; t < TAPS; ++t) {
                o0 += hk0[t] * sv[2 + j + t] + gk0[t] * dv[2 + j + t];
                o1 += hk1[t] * sv[2 + j + t] + gk1[t] * dv[2 + j + t];
            }
            o[2 * j] = o0; o[2 * j + 1] = o1;
        }
        float* dst = out + ((size_t)(b * 1024 + R0 + ri)) * 1024 + W0 + 8 * u;
        *reinterpret_cast<float4*>(dst)     = make_float4(o[0], o[1], o[2], o[3]);
        *reinterpret_cast<float4*>(dst + 4) = make_float4(o[4], o[5], o[6], o[7]);
    }
}

extern "C" void kernel_launch(void* const* d_in, const int* in_sizes, int n_in,
                              void* d_out, int out_size, void* d_ws, size_t ws_size,
                              hipStream_t stream) {
    const float* ss  = (const float*)d_in[0];
    const float* sd0 = (const float*)d_in[1];
    const float* sd1 = (const float*)d_in[2];
    const float* sd2 = (const float*)d_in[3];
    const float* ds0 = (const float*)d_in[4];
    const float* ds1 = (const float*)d_in[5];
    const float* ds2 = (const float*)d_in[6];
    const float* dd0 = (const float*)d_in[7];
    const float* dd1 = (const float*)d_in[8];
    const float* dd2 = (const float*)d_in[9];
    const float* h = (const float*)d_in[10];
    const float* g = (const float*)d_in[11];
    float* out = (float*)d_out;

    idwt3<<<2048, BLK, SM_FLOATS * 4, stream>>>(
        ss, sd0, sd1, sd2, ds0, ds1, ds2, dd0, dd1, dd2, h, g, out);
}